// Round 7
// baseline (384.781 us; speedup 1.0000x reference)
//
#include <hip/hip_runtime.h>
#include <hip/hip_bf16.h>
#include <cstdint>
#include <cstddef>

// GraphSAGE 2-layer: h1 = mean_agg(x@W1_l) + b1 + x@W1_r ; h2 = mean_agg(h1@W2_l) + b2 + h1@W2_r
// out = log_softmax(relu(h2))
//
// Round 7: GEMM1 rewritten LDS-free / barrier-free (k_gemm1r): each wave owns
// 16 rows x 128 cols; A frag loaded straight from x (fp32->bf16 in reg),
// B frag straight from L2-resident Wt. 46 k-steps, reg double-buffered
// (A 2-deep, B 1-deep). Rationale: R6 showed the barrier-drain k-loop is
// iteration-latency-bound (~constant 165us regardless of tile/bytes);
// barrier-free waves decorrelate and stream at HBM BW.

#define N_NODES 50000
#define N_EDGES 800000
#define F_IN    1433
#define KP      1472   // 23 * 64, zero-padded K
#define NK32    46     // KP / 32

typedef __attribute__((ext_vector_type(8))) short bf16x8;
typedef __attribute__((ext_vector_type(4))) float f32x4;

// ---- workspace layout (bytes) ----
static constexpr size_t OFF_H1PRE = 0;                               // 50000*128*4 = 25,600,000
static constexpr size_t OFF_H1    = OFF_H1PRE + 25600000;            // 50000*64*4  = 12,800,000
static constexpr size_t OFF_M2    = OFF_H1    + 12800000;            // 50000*64*4  = 12,800,000
static constexpr size_t OFF_DEG   = OFF_M2    + 12800000;            // 50000*4
static constexpr size_t OFF_OFFS  = OFF_DEG   + 200000;              // 50000*4
static constexpr size_t OFF_CUR   = OFF_OFFS  + 200000;              // 50000*4
static constexpr size_t OFF_ESRC  = OFF_CUR   + 200000;              // 800000*4
static constexpr size_t OFF_BSUM  = OFF_ESRC  + 3200000;             // 25*4 (pad 256)
static constexpr size_t OFF_BOFF  = OFF_BSUM  + 256;                 // 25*4 (pad 256)
static constexpr size_t OFF_WT    = OFF_BOFF  + 256;                 // 128*1472*2 = 376,832

__device__ inline ushort f2bf(float f) {
  union { float f; uint32_t u; } v; v.f = f;
  uint32_t u = v.u + 0x7FFFu + ((v.u >> 16) & 1u);   // RNE
  return (ushort)(u >> 16);
}

// ---- zero deg ----
__global__ __launch_bounds__(256) void k_zero_deg(int* __restrict__ deg) {
  int i = blockIdx.x * 256 + threadIdx.x;
  if (i < N_NODES) deg[i] = 0;
}

// ---- weight prep: Wt[c][k] = c<64 ? W1l[k][c] : W1r[k][c-64], bf16, k-padded ----
__global__ __launch_bounds__(256) void k_prep_w(const float* __restrict__ Wl,
                                                const float* __restrict__ Wr,
                                                ushort* __restrict__ Wt) {
  const int c = blockIdx.x;                       // 0..127
  const int k = blockIdx.y * 256 + threadIdx.x;
  if (k >= KP) return;
  float v = 0.f;
  if (k < F_IN) v = (c < 64) ? Wl[k * 64 + c] : Wr[k * 64 + (c - 64)];
  Wt[(size_t)c * KP + k] = f2bf(v);
}

// ---------------- GEMM1: LDS-free, barrier-free, per-wave 16 rows ----------------
// A frag (mfma_f32_16x16x32_bf16): lane holds row (lane&15), k (lane>>4)*8+[0..7].
// B frag n: lane holds Wt-row (outcol) n*16+(lane&15), same k positions.
// k>=F_IN tail: Wt zero-padded -> garbage A contributes 0; A flat idx clamped.
__global__ __launch_bounds__(256) void k_gemm1r(const float* __restrict__ x,
                                                const ushort* __restrict__ Wt,
                                                float* __restrict__ h1pre) {
  const int lane = threadIdx.x & 63;
  const int w    = threadIdx.x >> 6;
  const int row0 = blockIdx.x * 64 + w * 16;
  const int rr   = lane & 15;
  const int kq   = lane >> 4;            // 0..3
  int arow = row0 + rr; if (arow >= N_NODES) arow = N_NODES - 1;
  const size_t abase = (size_t)arow * F_IN + kq * 8;
  const size_t LIM   = (size_t)N_NODES * F_IN - 4;
  const ushort* bbase = Wt + (size_t)rr * KP + kq * 8;

  f32x4 acc[8] = {};

#define LDA(lo, hi, kk)                                             \
  do {                                                              \
    size_t i0 = abase + (size_t)(kk) * 32;                          \
    size_t i1 = i0 + 4;                                             \
    if (i0 > LIM) i0 = LIM;                                         \
    if (i1 > LIM) i1 = LIM;                                         \
    __builtin_memcpy(&lo, x + i0, 16);                              \
    __builtin_memcpy(&hi, x + i1, 16);                              \
  } while (0)

#define LDB(bb, kk)                                                 \
  do {                                                              \
    _Pragma("unroll")                                               \
    for (int n = 0; n < 8; ++n)                                     \
      __builtin_memcpy(&bb[n], bbase + (size_t)n * 16 * KP + (size_t)(kk) * 32, 16); \
  } while (0)

#define CVT(af, lo, hi)                                             \
  do {                                                              \
    _Pragma("unroll")                                               \
    for (int e = 0; e < 4; ++e) {                                   \
      af[e]     = (short)f2bf(lo[e]);                               \
      af[4 + e] = (short)f2bf(hi[e]);                               \
    }                                                               \
  } while (0)

#define MFMA8(af, bb)                                               \
  do {                                                              \
    _Pragma("unroll")                                               \
    for (int n = 0; n < 8; ++n)                                     \
      acc[n] = __builtin_amdgcn_mfma_f32_16x16x32_bf16(af, bb[n], acc[n], 0, 0, 0); \
  } while (0)

  f32x4 alo0, ahi0, alo1, ahi1;
  bf16x8 bb0[8], bb1[8];

  LDA(alo0, ahi0, 0);
  LDA(alo1, ahi1, 1);
  LDB(bb0, 0);

  for (int kk = 0; kk < NK32; kk += 2) {
    // even step kk
    LDB(bb1, kk + 1);
    {
      bf16x8 af; CVT(af, alo0, ahi0);
      if (kk + 2 < NK32) LDA(alo0, ahi0, kk + 2);
      MFMA8(af, bb0);
    }
    // odd step kk+1
    if (kk + 2 < NK32) LDB(bb0, kk + 2);
    {
      bf16x8 af; CVT(af, alo1, ahi1);
      if (kk + 3 < NK32) LDA(alo1, ahi1, kk + 3);
      MFMA8(af, bb1);
    }
  }
#undef LDA
#undef LDB
#undef CVT
#undef MFMA8

  // epilogue: D frag n: row = row0 + (lane>>4)*4 + r, col = n*16 + (lane&15)
  const int rbase = row0 + (lane >> 4) * 4;
#pragma unroll
  for (int n = 0; n < 8; ++n) {
    const int col = n * 16 + (lane & 15);
#pragma unroll
    for (int r = 0; r < 4; ++r) {
      int grow = rbase + r;
      if (grow < N_NODES) h1pre[(size_t)grow * 128 + col] = acc[n][r];
    }
  }
}

// ---------------- CSR build ----------------
__global__ void k_hist(const int* __restrict__ ei, int* __restrict__ deg) {
  int e = blockIdx.x * blockDim.x + threadIdx.x;
  if (e < N_EDGES) atomicAdd(&deg[ei[N_EDGES + e]], 1);
}

__global__ __launch_bounds__(256) void k_scan_a(const int* __restrict__ deg,
                                                int* __restrict__ off,
                                                int* __restrict__ blksum) {
  __shared__ int sd[256];
  const int t = threadIdx.x;
  const int base = blockIdx.x * 2048 + t * 8;
  int v[8];
  int s = 0;
#pragma unroll
  for (int j = 0; j < 8; ++j) {
    int i = base + j;
    v[j] = (i < N_NODES) ? deg[i] : 0;
    s += v[j];
  }
  sd[t] = s;
  __syncthreads();
  for (int o = 1; o < 256; o <<= 1) {
    int u = (t >= o) ? sd[t - o] : 0;
    __syncthreads();
    sd[t] += u;
    __syncthreads();
  }
  int excl = sd[t] - s;
#pragma unroll
  for (int j = 0; j < 8; ++j) {
    int i = base + j;
    if (i < N_NODES) off[i] = excl;
    excl += v[j];
  }
  if (t == 255) blksum[blockIdx.x] = sd[255];
}

// scan_c with fused chunk-offset computation: each 256-thread block lies in one
// 2048-chunk; wave 0 reduces blksum[0..c-1] via shfl.
__global__ __launch_bounds__(256) void k_scan_c(int* __restrict__ off, int* __restrict__ cur,
                                                const int* __restrict__ blksum) {
  __shared__ int boffs;
  const int c = blockIdx.x >> 3;            // 2048/256
  if (threadIdx.x < 64) {
    int v = ((int)threadIdx.x < c) ? blksum[threadIdx.x] : 0;
#pragma unroll
    for (int o = 32; o > 0; o >>= 1) v += __shfl_xor(v, o);
    if (threadIdx.x == 0) boffs = v;
  }
  __syncthreads();
  int i = blockIdx.x * 256 + threadIdx.x;
  if (i < N_NODES) {
    int v = off[i] + boffs;
    off[i] = v;
    cur[i] = v;
  }
}

__global__ void k_fill(const int* __restrict__ ei, int* __restrict__ cur,
                       int* __restrict__ esrc) {
  int e = blockIdx.x * blockDim.x + threadIdx.x;
  if (e < N_EDGES) {
    int s = ei[e];
    int d = ei[N_EDGES + e];
    int slot = atomicAdd(&cur[d], 1);
    esrc[slot] = s;
  }
}

// ---------------- aggregate layer 1: one wave per dst, 8-way unrolled gather ----------------
__global__ __launch_bounds__(256) void k_agg1(const float* __restrict__ h1pre,
                                              const int* __restrict__ off,
                                              const int* __restrict__ deg,
                                              const int* __restrict__ esrc,
                                              const float* __restrict__ b1,
                                              float* __restrict__ h1) {
  const int lane = threadIdx.x & 63;
  const int d = blockIdx.x * 4 + (threadIdx.x >> 6);
  if (d >= N_NODES) return;
  const int dg = deg[d];
  const int base = off[d];
  float a0 = 0.f, a1 = 0.f, a2 = 0.f, a3 = 0.f;
  float a4 = 0.f, a5 = 0.f, a6 = 0.f, a7 = 0.f;
  int j = 0;
  for (; j + 8 <= dg; j += 8) {
    int s0 = esrc[base + j],     s1 = esrc[base + j + 1];
    int s2 = esrc[base + j + 2], s3 = esrc[base + j + 3];
    int s4 = esrc[base + j + 4], s5 = esrc[base + j + 5];
    int s6 = esrc[base + j + 6], s7 = esrc[base + j + 7];
    a0 += h1pre[(size_t)s0 * 128 + lane];
    a1 += h1pre[(size_t)s1 * 128 + lane];
    a2 += h1pre[(size_t)s2 * 128 + lane];
    a3 += h1pre[(size_t)s3 * 128 + lane];
    a4 += h1pre[(size_t)s4 * 128 + lane];
    a5 += h1pre[(size_t)s5 * 128 + lane];
    a6 += h1pre[(size_t)s6 * 128 + lane];
    a7 += h1pre[(size_t)s7 * 128 + lane];
  }
  for (; j + 4 <= dg; j += 4) {
    int s0 = esrc[base + j],     s1 = esrc[base + j + 1];
    int s2 = esrc[base + j + 2], s3 = esrc[base + j + 3];
    a0 += h1pre[(size_t)s0 * 128 + lane];
    a1 += h1pre[(size_t)s1 * 128 + lane];
    a2 += h1pre[(size_t)s2 * 128 + lane];
    a3 += h1pre[(size_t)s3 * 128 + lane];
  }
  for (; j < dg; ++j) a0 += h1pre[(size_t)esrc[base + j] * 128 + lane];
  float acc = ((a0 + a1) + (a2 + a3)) + ((a4 + a5) + (a6 + a7));
  const float inv = (dg > 0) ? 1.f / (float)dg : 0.f;
  h1[(size_t)d * 64 + lane] = acc * inv + b1[lane] + h1pre[(size_t)d * 128 + 64 + lane];
}

// ---------------- GEMM2: h1[50000,64] @ [W2_l|W2_r][64,64] -> m2[50000,64] ----------------
__global__ __launch_bounds__(256) void k_gemm2(const float* __restrict__ h1,
                                               const float* __restrict__ W2l,
                                               const float* __restrict__ W2r,
                                               float* __restrict__ m2) {
  __shared__ __align__(16) float Ws[64][68];
  __shared__ __align__(16) float Hs[32][68];
  const int t = threadIdx.x;
#pragma unroll
  for (int i = 0; i < 16; ++i) {
    int idx = t + 256 * i;
    int k = idx >> 6, c = idx & 63;
    Ws[k][c] = (c < 32) ? W2l[k * 32 + c] : W2r[k * 32 + (c - 32)];
  }
  const int r0 = blockIdx.x * 32;
#pragma unroll
  for (int i = 0; i < 8; ++i) {
    int idx = t + 256 * i;
    int r = idx >> 6, c = idx & 63;
    int gr = r0 + r;
    Hs[r][c] = (gr < N_NODES) ? h1[(size_t)gr * 64 + c] : 0.f;
  }
  __syncthreads();
  const int rl = t >> 3;
  const int c0 = (t & 7) * 8;
  float acc[8] = {};
#pragma unroll 8
  for (int k = 0; k < 64; ++k) {
    float hv = Hs[rl][k];
#pragma unroll
    for (int j = 0; j < 8; ++j) acc[j] = fmaf(hv, Ws[k][c0 + j], acc[j]);
  }
  const int gr = r0 + rl;
  if (gr < N_NODES) {
    *(float4*)(&m2[(size_t)gr * 64 + c0])     = make_float4(acc[0], acc[1], acc[2], acc[3]);
    *(float4*)(&m2[(size_t)gr * 64 + c0 + 4]) = make_float4(acc[4], acc[5], acc[6], acc[7]);
  }
}

// ---------------- aggregate layer 2 + relu + log_softmax, 8-way unrolled ----------------
__global__ __launch_bounds__(256) void k_agg2(const float* __restrict__ m2,
                                              const int* __restrict__ off,
                                              const int* __restrict__ deg,
                                              const int* __restrict__ esrc,
                                              const float* __restrict__ b2,
                                              float* __restrict__ out) {
  const int lane = threadIdx.x & 63;
  const int half = lane >> 5;
  const int f = lane & 31;
  const int d = blockIdx.x * 8 + ((threadIdx.x >> 6) << 1) + half;  // 50000 % 8 == 0
  const int dg = deg[d];
  const int base = off[d];
  float a0 = 0.f, a1 = 0.f, a2 = 0.f, a3 = 0.f;
  float a4 = 0.f, a5 = 0.f, a6 = 0.f, a7 = 0.f;
  int j = 0;
  for (; j + 8 <= dg; j += 8) {
    int s0 = esrc[base + j],     s1 = esrc[base + j + 1];
    int s2 = esrc[base + j + 2], s3 = esrc[base + j + 3];
    int s4 = esrc[base + j + 4], s5 = esrc[base + j + 5];
    int s6 = esrc[base + j + 6], s7 = esrc[base + j + 7];
    a0 += m2[(size_t)s0 * 64 + f];
    a1 += m2[(size_t)s1 * 64 + f];
    a2 += m2[(size_t)s2 * 64 + f];
    a3 += m2[(size_t)s3 * 64 + f];
    a4 += m2[(size_t)s4 * 64 + f];
    a5 += m2[(size_t)s5 * 64 + f];
    a6 += m2[(size_t)s6 * 64 + f];
    a7 += m2[(size_t)s7 * 64 + f];
  }
  for (; j + 4 <= dg; j += 4) {
    int s0 = esrc[base + j],     s1 = esrc[base + j + 1];
    int s2 = esrc[base + j + 2], s3 = esrc[base + j + 3];
    a0 += m2[(size_t)s0 * 64 + f];
    a1 += m2[(size_t)s1 * 64 + f];
    a2 += m2[(size_t)s2 * 64 + f];
    a3 += m2[(size_t)s3 * 64 + f];
  }
  for (; j < dg; ++j) a0 += m2[(size_t)esrc[base + j] * 64 + f];
  float acc = ((a0 + a1) + (a2 + a3)) + ((a4 + a5) + (a6 + a7));
  const float inv = (dg > 0) ? 1.f / (float)dg : 0.f;
  float v = acc * inv + b2[f] + m2[(size_t)d * 64 + 32 + f];
  v = fmaxf(v, 0.f);
  float m = v;
#pragma unroll
  for (int o = 16; o > 0; o >>= 1) m = fmaxf(m, __shfl_xor(m, o, 32));
  float e = expf(v - m);
  float sum = e;
#pragma unroll
  for (int o = 16; o > 0; o >>= 1) sum += __shfl_xor(sum, o, 32);
  out[(size_t)d * 32 + f] = v - m - logf(sum);
}

extern "C" void kernel_launch(void* const* d_in, const int* in_sizes, int n_in,
                              void* d_out, int out_size, void* d_ws, size_t ws_size,
                              hipStream_t stream) {
  const float* x   = (const float*)d_in[0];
  const int*   ei  = (const int*)d_in[1];
  const float* W1l = (const float*)d_in[2];
  const float* b1  = (const float*)d_in[3];
  const float* W1r = (const float*)d_in[4];
  const float* W2l = (const float*)d_in[5];
  const float* b2  = (const float*)d_in[6];
  const float* W2r = (const float*)d_in[7];
  float* out = (float*)d_out;

  char* ws = (char*)d_ws;
  float*  h1pre = (float*)(ws + OFF_H1PRE);
  float*  h1    = (float*)(ws + OFF_H1);
  float*  m2    = (float*)(ws + OFF_M2);
  int*    deg   = (int*)(ws + OFF_DEG);
  int*    off   = (int*)(ws + OFF_OFFS);
  int*    cur   = (int*)(ws + OFF_CUR);
  int*    esrc  = (int*)(ws + OFF_ESRC);
  int*    bsum  = (int*)(ws + OFF_BSUM);
  ushort* Wt    = (ushort*)(ws + OFF_WT);

  k_zero_deg<<<(N_NODES + 255) / 256, 256, 0, stream>>>(deg);

  {
    dim3 g(128, (KP + 255) / 256);
    k_prep_w<<<g, 256, 0, stream>>>(W1l, W1r, Wt);
  }
  k_gemm1r<<<(N_NODES + 63) / 64, 256, 0, stream>>>(x, Wt, h1pre);

  k_hist<<<(N_EDGES + 255) / 256, 256, 0, stream>>>(ei, deg);
  k_scan_a<<<25, 256, 0, stream>>>(deg, off, bsum);
  k_scan_c<<<(N_NODES + 255) / 256, 256, 0, stream>>>(off, cur, bsum);
  k_fill<<<(N_EDGES + 255) / 256, 256, 0, stream>>>(ei, cur, esrc);

  k_agg1<<<N_NODES / 4, 256, 0, stream>>>(h1pre, off, deg, esrc, b1, h1);
  k_gemm2<<<(N_NODES + 31) / 32, 256, 0, stream>>>(h1, W2l, W2r, m2);
  k_agg2<<<N_NODES / 8, 256, 0, stream>>>(m2, off, deg, esrc, b2, out);
}

// Round 9
// 313.765 us; speedup vs baseline: 1.2263x; 1.2263x over previous
//
#include <hip/hip_runtime.h>
#include <hip/hip_bf16.h>
#include <cstdint>
#include <cstddef>

// GraphSAGE 2-layer: h1 = mean_agg(x@W1_l) + b1 + x@W1_r ; h2 = mean_agg(h1@W2_l) + b2 + h1@W2_r
// out = log_softmax(relu(h2))
//
// Round 9: R8's counted-vmcnt multi-wave pipeline raced (absmax 4.5) -> dropped.
// GEMM1 = barrier-free per-wave streaming (R7 structure, which was CORRECT),
// fixed: (a) B repacked to Wt2[c/16][k/8][16][8] so fragment loads coalesce
// (R7 scattered 16B reads across 2944B-strided rows); (b) __launch_bounds__(256,1)
// so the allocator keeps the 2-deep A + 2-deep B register pipeline (R7 got
// VGPR=68 -> compiler serialized B loads at L2 latency = 254us).
// No inter-wave sync anywhere in gemm1 -> no race surface.

#define N_NODES 50000
#define N_EDGES 800000
#define F_IN    1433
#define KP      1472   // 23 * 64, zero-padded K
#define NK32    46     // KP / 32
#define NKB     184    // KP / 8

typedef __attribute__((ext_vector_type(8))) short bf16x8;
typedef __attribute__((ext_vector_type(4))) float f32x4;

// ---- workspace layout (bytes) ----
static constexpr size_t OFF_H1PRE = 0;                               // 50000*128*4 = 25,600,000
static constexpr size_t OFF_H1    = OFF_H1PRE + 25600000;            // 50000*64*4  = 12,800,000
static constexpr size_t OFF_M2    = OFF_H1    + 12800000;            // 50000*64*4  = 12,800,000
static constexpr size_t OFF_DEG   = OFF_M2    + 12800000;            // 50000*4
static constexpr size_t OFF_OFFS  = OFF_DEG   + 200000;              // 50000*4
static constexpr size_t OFF_CUR   = OFF_OFFS  + 200000;              // 50000*4
static constexpr size_t OFF_ESRC  = OFF_CUR   + 200000;              // 800000*4
static constexpr size_t OFF_BSUM  = OFF_ESRC  + 3200000;             // 25*4 (pad 256)
static constexpr size_t OFF_BOFF  = OFF_BSUM  + 256;                 // 25*4 (pad 256)
static constexpr size_t OFF_WT    = OFF_BOFF  + 256;                 // 128*1472*2 = 376,832

__device__ inline ushort f2bf(float f) {
  union { float f; uint32_t u; } v; v.f = f;
  uint32_t u = v.u + 0x7FFFu + ((v.u >> 16) & 1u);   // RNE
  return (ushort)(u >> 16);
}

// ---- zero deg ----
__global__ __launch_bounds__(256) void k_zero_deg(int* __restrict__ deg) {
  int i = blockIdx.x * 256 + threadIdx.x;
  if (i < N_NODES) deg[i] = 0;
}

// ---- weight prep: Wt2[c>>4][k>>3][c&15][k&7] = bf16(c<64 ? W1l[k][c] : W1r[k][c-64])
// (c = out-col 0..127, k 0..1471 zero-padded). A wave's B-fragment load is then
// 16 lanes x 16B over one contiguous 256B segment.
__global__ __launch_bounds__(256) void k_prep_w2(const float* __restrict__ Wl,
                                                 const float* __restrict__ Wr,
                                                 ushort* __restrict__ Wt2) {
  const int c = blockIdx.x;                       // 0..127
  const int k = blockIdx.y * 256 + threadIdx.x;
  if (k >= KP) return;
  float v = 0.f;
  if (k < F_IN) v = (c < 64) ? Wl[k * 64 + c] : Wr[k * 64 + (c - 64)];
  size_t idx = ((((size_t)(c >> 4) * NKB + (k >> 3)) * 16) + (c & 15)) * 8 + (k & 7);
  Wt2[idx] = f2bf(v);
}

// ---------------- GEMM1: barrier-free, per-wave 16 rows x 128 cols ----------------
// A frag (mfma_f32_16x16x32_bf16): lane holds row (lane&15), k (lane>>4)*8+[0..7],
// loaded straight from fp32 x (clamped flat index; zero-padded Wt2 masks K tail).
// B frag n from Wt2: lane offset ((n*NKB + kk*4 + kq)*16 + rr)*8 ushorts — coalesced.
// 2-deep register pipeline on both A and B; launch_bounds(256,1) keeps it in VGPRs.
__global__ __launch_bounds__(256, 1) void k_gemm1r(const float* __restrict__ x,
                                                   const ushort* __restrict__ Wt2,
                                                   float* __restrict__ h1pre) {
  const int lane = threadIdx.x & 63;
  const int w    = threadIdx.x >> 6;
  const int row0 = (blockIdx.x * 4 + w) * 16;
  const int rr   = lane & 15;
  const int kq   = lane >> 4;            // 0..3
  int arow = row0 + rr; if (arow >= N_NODES) arow = N_NODES - 1;
  const size_t abase = (size_t)arow * F_IN + kq * 8;
  const size_t LIM   = (size_t)N_NODES * F_IN - 4;
  const ushort* bbase = Wt2 + ((size_t)(kq * 16) + rr) * 8;

  f32x4 acc[8] = {};

#define LDA(lo, hi, kk)                                             \
  do {                                                              \
    size_t i0 = abase + (size_t)(kk) * 32;                          \
    size_t i1 = i0 + 4;                                             \
    if (i0 > LIM) i0 = LIM;                                         \
    if (i1 > LIM) i1 = LIM;                                         \
    __builtin_memcpy(&lo, x + i0, 16);                              \
    __builtin_memcpy(&hi, x + i1, 16);                              \
  } while (0)

#define LDB(bb, kk)                                                 \
  do {                                                              \
    _Pragma("unroll")                                               \
    for (int n = 0; n < 8; ++n)                                     \
      __builtin_memcpy(&bb[n], bbase + ((size_t)n * NKB + (size_t)(kk) * 4) * 128, 16); \
  } while (0)

#define CVT(af, lo, hi)                                             \
  do {                                                              \
    _Pragma("unroll")                                               \
    for (int e = 0; e < 4; ++e) {                                   \
      af[e]     = (short)f2bf(lo[e]);                               \
      af[4 + e] = (short)f2bf(hi[e]);                               \
    }                                                               \
  } while (0)

#define MFMA8(af, bb)                                               \
  do {                                                              \
    _Pragma("unroll")                                               \
    for (int n = 0; n < 8; ++n)                                     \
      acc[n] = __builtin_amdgcn_mfma_f32_16x16x32_bf16(af, bb[n], acc[n], 0, 0, 0); \
  } while (0)

  f32x4 alo0, ahi0, alo1, ahi1;
  bf16x8 bb0[8], bb1[8];

  LDA(alo0, ahi0, 0);
  LDA(alo1, ahi1, 1);
  LDB(bb0, 0);

  for (int kk = 0; kk < NK32; kk += 2) {
    // even step kk
    LDB(bb1, kk + 1);
    {
      bf16x8 af; CVT(af, alo0, ahi0);
      if (kk + 2 < NK32) LDA(alo0, ahi0, kk + 2);
      MFMA8(af, bb0);
    }
    // odd step kk+1
    if (kk + 2 < NK32) LDB(bb0, kk + 2);
    {
      bf16x8 af; CVT(af, alo1, ahi1);
      if (kk + 3 < NK32) LDA(alo1, ahi1, kk + 3);
      MFMA8(af, bb1);
    }
  }
#undef LDA
#undef LDB
#undef CVT
#undef MFMA8

  // epilogue: D frag n: row = row0 + (lane>>4)*4 + r, col = n*16 + (lane&15)
  const int rbase = row0 + (lane >> 4) * 4;
#pragma unroll
  for (int n = 0; n < 8; ++n) {
    const int col = n * 16 + (lane & 15);
#pragma unroll
    for (int r = 0; r < 4; ++r) {
      int grow = rbase + r;
      if (grow < N_NODES) h1pre[(size_t)grow * 128 + col] = acc[n][r];
    }
  }
}

// ---------------- CSR build ----------------
__global__ void k_hist(const int* __restrict__ ei, int* __restrict__ deg) {
  int e = blockIdx.x * blockDim.x + threadIdx.x;
  if (e < N_EDGES) atomicAdd(&deg[ei[N_EDGES + e]], 1);
}

__global__ __launch_bounds__(256) void k_scan_a(const int* __restrict__ deg,
                                                int* __restrict__ off,
                                                int* __restrict__ blksum) {
  __shared__ int sd[256];
  const int t = threadIdx.x;
  const int base = blockIdx.x * 2048 + t * 8;
  int v[8];
  int s = 0;
#pragma unroll
  for (int j = 0; j < 8; ++j) {
    int i = base + j;
    v[j] = (i < N_NODES) ? deg[i] : 0;
    s += v[j];
  }
  sd[t] = s;
  __syncthreads();
  for (int o = 1; o < 256; o <<= 1) {
    int u = (t >= o) ? sd[t - o] : 0;
    __syncthreads();
    sd[t] += u;
    __syncthreads();
  }
  int excl = sd[t] - s;
#pragma unroll
  for (int j = 0; j < 8; ++j) {
    int i = base + j;
    if (i < N_NODES) off[i] = excl;
    excl += v[j];
  }
  if (t == 255) blksum[blockIdx.x] = sd[255];
}

// scan_c with fused chunk-offset computation: each 256-thread block lies in one
// 2048-chunk; wave 0 reduces blksum[0..c-1] via shfl.
__global__ __launch_bounds__(256) void k_scan_c(int* __restrict__ off, int* __restrict__ cur,
                                                const int* __restrict__ blksum) {
  __shared__ int boffs;
  const int c = blockIdx.x >> 3;            // 2048/256
  if (threadIdx.x < 64) {
    int v = ((int)threadIdx.x < c) ? blksum[threadIdx.x] : 0;
#pragma unroll
    for (int o = 32; o > 0; o >>= 1) v += __shfl_xor(v, o);
    if (threadIdx.x == 0) boffs = v;
  }
  __syncthreads();
  int i = blockIdx.x * 256 + threadIdx.x;
  if (i < N_NODES) {
    int v = off[i] + boffs;
    off[i] = v;
    cur[i] = v;
  }
}

__global__ void k_fill(const int* __restrict__ ei, int* __restrict__ cur,
                       int* __restrict__ esrc) {
  int e = blockIdx.x * blockDim.x + threadIdx.x;
  if (e < N_EDGES) {
    int s = ei[e];
    int d = ei[N_EDGES + e];
    int slot = atomicAdd(&cur[d], 1);
    esrc[slot] = s;
  }
}

// ---------------- aggregate layer 1: one wave per dst, 8-way unrolled gather ----------------
__global__ __launch_bounds__(256) void k_agg1(const float* __restrict__ h1pre,
                                              const int* __restrict__ off,
                                              const int* __restrict__ deg,
                                              const int* __restrict__ esrc,
                                              const float* __restrict__ b1,
                                              float* __restrict__ h1) {
  const int lane = threadIdx.x & 63;
  const int d = blockIdx.x * 4 + (threadIdx.x >> 6);
  if (d >= N_NODES) return;
  const int dg = deg[d];
  const int base = off[d];
  float a0 = 0.f, a1 = 0.f, a2 = 0.f, a3 = 0.f;
  float a4 = 0.f, a5 = 0.f, a6 = 0.f, a7 = 0.f;
  int j = 0;
  for (; j + 8 <= dg; j += 8) {
    int s0 = esrc[base + j],     s1 = esrc[base + j + 1];
    int s2 = esrc[base + j + 2], s3 = esrc[base + j + 3];
    int s4 = esrc[base + j + 4], s5 = esrc[base + j + 5];
    int s6 = esrc[base + j + 6], s7 = esrc[base + j + 7];
    a0 += h1pre[(size_t)s0 * 128 + lane];
    a1 += h1pre[(size_t)s1 * 128 + lane];
    a2 += h1pre[(size_t)s2 * 128 + lane];
    a3 += h1pre[(size_t)s3 * 128 + lane];
    a4 += h1pre[(size_t)s4 * 128 + lane];
    a5 += h1pre[(size_t)s5 * 128 + lane];
    a6 += h1pre[(size_t)s6 * 128 + lane];
    a7 += h1pre[(size_t)s7 * 128 + lane];
  }
  for (; j + 4 <= dg; j += 4) {
    int s0 = esrc[base + j],     s1 = esrc[base + j + 1];
    int s2 = esrc[base + j + 2], s3 = esrc[base + j + 3];
    a0 += h1pre[(size_t)s0 * 128 + lane];
    a1 += h1pre[(size_t)s1 * 128 + lane];
    a2 += h1pre[(size_t)s2 * 128 + lane];
    a3 += h1pre[(size_t)s3 * 128 + lane];
  }
  for (; j < dg; ++j) a0 += h1pre[(size_t)esrc[base + j] * 128 + lane];
  float acc = ((a0 + a1) + (a2 + a3)) + ((a4 + a5) + (a6 + a7));
  const float inv = (dg > 0) ? 1.f / (float)dg : 0.f;
  h1[(size_t)d * 64 + lane] = acc * inv + b1[lane] + h1pre[(size_t)d * 128 + 64 + lane];
}

// ---------------- GEMM2: h1[50000,64] @ [W2_l|W2_r][64,64] -> m2[50000,64] ----------------
__global__ __launch_bounds__(256) void k_gemm2(const float* __restrict__ h1,
                                               const float* __restrict__ W2l,
                                               const float* __restrict__ W2r,
                                               float* __restrict__ m2) {
  __shared__ __align__(16) float Ws[64][68];
  __shared__ __align__(16) float Hs[32][68];
  const int t = threadIdx.x;
#pragma unroll
  for (int i = 0; i < 16; ++i) {
    int idx = t + 256 * i;
    int k = idx >> 6, c = idx & 63;
    Ws[k][c] = (c < 32) ? W2l[k * 32 + c] : W2r[k * 32 + (c - 32)];
  }
  const int r0 = blockIdx.x * 32;
#pragma unroll
  for (int i = 0; i < 8; ++i) {
    int idx = t + 256 * i;
    int r = idx >> 6, c = idx & 63;
    int gr = r0 + r;
    Hs[r][c] = (gr < N_NODES) ? h1[(size_t)gr * 64 + c] : 0.f;
  }
  __syncthreads();
  const int rl = t >> 3;
  const int c0 = (t & 7) * 8;
  float acc[8] = {};
#pragma unroll 8
  for (int k = 0; k < 64; ++k) {
    float hv = Hs[rl][k];
#pragma unroll
    for (int j = 0; j < 8; ++j) acc[j] = fmaf(hv, Ws[k][c0 + j], acc[j]);
  }
  const int gr = r0 + rl;
  if (gr < N_NODES) {
    *(float4*)(&m2[(size_t)gr * 64 + c0])     = make_float4(acc[0], acc[1], acc[2], acc[3]);
    *(float4*)(&m2[(size_t)gr * 64 + c0 + 4]) = make_float4(acc[4], acc[5], acc[6], acc[7]);
  }
}

// ---------------- aggregate layer 2 + relu + log_softmax, 8-way unrolled ----------------
__global__ __launch_bounds__(256) void k_agg2(const float* __restrict__ m2,
                                              const int* __restrict__ off,
                                              const int* __restrict__ deg,
                                              const int* __restrict__ esrc,
                                              const float* __restrict__ b2,
                                              float* __restrict__ out) {
  const int lane = threadIdx.x & 63;
  const int half = lane >> 5;
  const int f = lane & 31;
  const int d = blockIdx.x * 8 + ((threadIdx.x >> 6) << 1) + half;  // 50000 % 8 == 0
  const int dg = deg[d];
  const int base = off[d];
  float a0 = 0.f, a1 = 0.f, a2 = 0.f, a3 = 0.f;
  float a4 = 0.f, a5 = 0.f, a6 = 0.f, a7 = 0.f;
  int j = 0;
  for (; j + 8 <= dg; j += 8) {
    int s0 = esrc[base + j],     s1 = esrc[base + j + 1];
    int s2 = esrc[base + j + 2], s3 = esrc[base + j + 3];
    int s4 = esrc[base + j + 4], s5 = esrc[base + j + 5];
    int s6 = esrc[base + j + 6], s7 = esrc[base + j + 7];
    a0 += m2[(size_t)s0 * 64 + f];
    a1 += m2[(size_t)s1 * 64 + f];
    a2 += m2[(size_t)s2 * 64 + f];
    a3 += m2[(size_t)s3 * 64 + f];
    a4 += m2[(size_t)s4 * 64 + f];
    a5 += m2[(size_t)s5 * 64 + f];
    a6 += m2[(size_t)s6 * 64 + f];
    a7 += m2[(size_t)s7 * 64 + f];
  }
  for (; j + 4 <= dg; j += 4) {
    int s0 = esrc[base + j],     s1 = esrc[base + j + 1];
    int s2 = esrc[base + j + 2], s3 = esrc[base + j + 3];
    a0 += m2[(size_t)s0 * 64 + f];
    a1 += m2[(size_t)s1 * 64 + f];
    a2 += m2[(size_t)s2 * 64 + f];
    a3 += m2[(size_t)s3 * 64 + f];
  }
  for (; j < dg; ++j) a0 += m2[(size_t)esrc[base + j] * 64 + f];
  float acc = ((a0 + a1) + (a2 + a3)) + ((a4 + a5) + (a6 + a7));
  const float inv = (dg > 0) ? 1.f / (float)dg : 0.f;
  float v = acc * inv + b2[f] + m2[(size_t)d * 64 + 32 + f];
  v = fmaxf(v, 0.f);
  float m = v;
#pragma unroll
  for (int o = 16; o > 0; o >>= 1) m = fmaxf(m, __shfl_xor(m, o, 32));
  float e = expf(v - m);
  float sum = e;
#pragma unroll
  for (int o = 16; o > 0; o >>= 1) sum += __shfl_xor(sum, o, 32);
  out[(size_t)d * 32 + f] = v - m - logf(sum);
}

extern "C" void kernel_launch(void* const* d_in, const int* in_sizes, int n_in,
                              void* d_out, int out_size, void* d_ws, size_t ws_size,
                              hipStream_t stream) {
  const float* x   = (const float*)d_in[0];
  const int*   ei  = (const int*)d_in[1];
  const float* W1l = (const float*)d_in[2];
  const float* b1  = (const float*)d_in[3];
  const float* W1r = (const float*)d_in[4];
  const float* W2l = (const float*)d_in[5];
  const float* b2  = (const float*)d_in[6];
  const float* W2r = (const float*)d_in[7];
  float* out = (float*)d_out;

  char* ws = (char*)d_ws;
  float*  h1pre = (float*)(ws + OFF_H1PRE);
  float*  h1    = (float*)(ws + OFF_H1);
  float*  m2    = (float*)(ws + OFF_M2);
  int*    deg   = (int*)(ws + OFF_DEG);
  int*    off   = (int*)(ws + OFF_OFFS);
  int*    cur   = (int*)(ws + OFF_CUR);
  int*    esrc  = (int*)(ws + OFF_ESRC);
  int*    bsum  = (int*)(ws + OFF_BSUM);
  ushort* Wt2   = (ushort*)(ws + OFF_WT);

  k_zero_deg<<<(N_NODES + 255) / 256, 256, 0, stream>>>(deg);

  {
    dim3 g(128, (KP + 255) / 256);
    k_prep_w2<<<g, 256, 0, stream>>>(W1l, W1r, Wt2);
  }
  k_gemm1r<<<(N_NODES + 63) / 64, 256, 0, stream>>>(x, Wt2, h1pre);

  k_hist<<<(N_EDGES + 255) / 256, 256, 0, stream>>>(ei, deg);
  k_scan_a<<<25, 256, 0, stream>>>(deg, off, bsum);
  k_scan_c<<<(N_NODES + 255) / 256, 256, 0, stream>>>(off, cur, bsum);
  k_fill<<<(N_EDGES + 255) / 256, 256, 0, stream>>>(ei, cur, esrc);

  k_agg1<<<N_NODES / 4, 256, 0, stream>>>(h1pre, off, deg, esrc, b1, h1);
  k_gemm2<<<(N_NODES + 31) / 32, 256, 0, stream>>>(h1, W2l, W2r, m2);
  k_agg2<<<N_NODES / 8, 256, 0, stream>>>(m2, off, deg, esrc, b2, out);
}

// Round 10
// 259.244 us; speedup vs baseline: 1.4842x; 1.2103x over previous
//
#include <hip/hip_runtime.h>
#include <hip/hip_bf16.h>
#include <cstdint>
#include <cstddef>

// GraphSAGE 2-layer: h1 = mean_agg(x@W1_l) + b1 + x@W1_r ; h2 = mean_agg(h1@W2_l) + b2 + h1@W2_r
// out = log_softmax(relu(h2))
//
// Round 10: GEMM1 = chunked-barrier staging (k_gemm1c). BK=256 mega-chunks,
// single-buffered 80KB LDS (A 16KB + B 64KB as 4x the proven R6 64-k subtile
// layout). Only 2 __syncthreads per chunk (12 total vs R6's 23 full drains).
// A loads for chunk c+1 issue right after the opening barrier -> fly under
// ~2000cy of MFMA, complete before the closing-barrier drain. No manual
// vmcnt, no multi-wave race surface (R8 lesson); compiler-inserted waits only.
// R9 lesson: hipcc sinks register prefetches (VGPR=68 despite launch_bounds);
// LDS staging + rare barriers is the safe path.

#define N_NODES 50000
#define N_EDGES 800000
#define F_IN    1433
#define KP      1472   // 23 * 64, zero-padded K
#define NCH     6      // chunks of 256 k (5x256 + 192)

typedef __attribute__((ext_vector_type(8))) short bf16x8;
typedef __attribute__((ext_vector_type(4))) float f32x4;

// ---- workspace layout (bytes) ----
static constexpr size_t OFF_H1PRE = 0;                               // 50000*128*4 = 25,600,000
static constexpr size_t OFF_H1    = OFF_H1PRE + 25600000;            // 50000*64*4  = 12,800,000
static constexpr size_t OFF_M2    = OFF_H1    + 12800000;            // 50000*64*4  = 12,800,000
static constexpr size_t OFF_DEG   = OFF_M2    + 12800000;            // 50000*4
static constexpr size_t OFF_OFFS  = OFF_DEG   + 200000;              // 50000*4
static constexpr size_t OFF_CUR   = OFF_OFFS  + 200000;              // 50000*4
static constexpr size_t OFF_ESRC  = OFF_CUR   + 200000;              // 800000*4
static constexpr size_t OFF_BSUM  = OFF_ESRC  + 3200000;             // 25*4 (pad 256)
static constexpr size_t OFF_BOFF  = OFF_BSUM  + 256;                 // 25*4 (pad 256)
static constexpr size_t OFF_WT    = OFF_BOFF  + 256;                 // 128*1472*2 = 376,832

__device__ inline ushort f2bf(float f) {
  union { float f; uint32_t u; } v; v.f = f;
  uint32_t u = v.u + 0x7FFFu + ((v.u >> 16) & 1u);   // RNE
  return (ushort)(u >> 16);
}

__device__ __forceinline__ void gload_lds16(const void* g, void* l) {
  __builtin_amdgcn_global_load_lds(
      (const __attribute__((address_space(1))) void*)g,
      (__attribute__((address_space(3))) void*)l, 16, 0, 0);
}

// ---- zero deg ----
__global__ __launch_bounds__(256) void k_zero_deg(int* __restrict__ deg) {
  int i = blockIdx.x * 256 + threadIdx.x;
  if (i < N_NODES) deg[i] = 0;
}

// ---- weight prep: Wt[c][k] = c<64 ? W1l[k][c] : W1r[k][c-64], bf16, k-padded ----
__global__ __launch_bounds__(256) void k_prep_w(const float* __restrict__ Wl,
                                                const float* __restrict__ Wr,
                                                ushort* __restrict__ Wt) {
  const int c = blockIdx.x;                       // 0..127
  const int k = blockIdx.y * 256 + threadIdx.x;
  if (k >= KP) return;
  float v = 0.f;
  if (k < F_IN) v = (c < 64) ? Wl[k * 64 + c] : Wr[k * 64 + (c - 64)];
  Wt[(size_t)c * KP + k] = f2bf(v);
}

// ---------------- GEMM1: BM=32, BN=128, chunked BK=256, 2 barriers/chunk ----------------
// LDS: As[4 subs][32 rows][64 k] bf16 + Bs[4 subs][128 rows][64 k] bf16, each
// subtile uses R6's proven XOR swizzle (16B slot s stored at s^(row&7)).
// Per chunk: {cvt+ds_write A (from regs loaded last chunk), gload_lds B} ->
// barrier -> issue next chunk's A loads -> 8 MFMA k-steps -> barrier.
__global__ __launch_bounds__(256) void k_gemm1c(const float* __restrict__ x,
                                                const ushort* __restrict__ Wt,
                                                float* __restrict__ h1pre) {
  __shared__ __align__(16) ushort As[4][32 * 64];    // 16 KB
  __shared__ __align__(16) ushort Bs[4][128 * 64];   // 64 KB
  const int t    = threadIdx.x;
  const int lane = t & 63;
  const int w    = t >> 6;             // 0..3
  const int wr   = w >> 1;             // row band (16 rows)
  const int wc   = w & 1;              // col band (64 cols)
  const int row0 = blockIdx.x * 32;

  // A staging: thread t -> row ar (0..31, 8 threads/row), 8-float chunk aq (0..7)
  const int ar = t >> 3;
  const int aq = t & 7;
  const size_t abase = (size_t)(row0 + ar) * F_IN + aq * 8;
  const size_t LIM   = (size_t)N_NODES * F_IN - 4;   // clamp: valid garbage, zero weights
  const int aoff = ar * 64;                          // ushort offset of row
  const int asw  = (aq ^ (ar & 7)) * 8;              // swizzled slot, ushorts

  // B staging per-wave invariants (inverse-swizzled source, linear LDS dest)
  const int lr = lane >> 3, lt = lane & 7;
  const ushort* b_src[4];
  ushort* b_dst[4];
#pragma unroll
  for (int j = 0; j < 4; ++j) {
    int r = (w * 4 + j) * 8 + lr;                 // 0..127
    b_src[j] = Wt + (size_t)r * KP + (lt ^ (r & 7)) * 8;
    b_dst[j] = (ushort*)&Bs[0][(w * 4 + j) * 512];
  }

  f32x4 acc[4] = {};
  f32x4 av[4][2];                      // A prefetch regs: 4 subs x 32B

#define LOADA_CHUNK(kbase)                                          \
  do {                                                              \
    _Pragma("unroll")                                               \
    for (int s = 0; s < 4; ++s) {                                   \
      size_t i0 = abase + (size_t)(kbase) + s * 64;                 \
      size_t i1 = i0 + 4;                                           \
      if (i0 > LIM) i0 = LIM;                                       \
      if (i1 > LIM) i1 = LIM;                                       \
      __builtin_memcpy(&av[s][0], x + i0, 16);                      \
      __builtin_memcpy(&av[s][1], x + i1, 16);                      \
    }                                                               \
  } while (0)

  // prologue: A for chunk 0 (latency exposed once)
  LOADA_CHUNK(0);

  for (int c = 0; c < NCH; ++c) {
    const int kbase = c * 256;
    const int nsub = (c < 5) ? 4 : 3;
    // write A (regs -> cvt -> swizzled ds_write)
#pragma unroll
    for (int s = 0; s < 4; ++s) {
      if (s < nsub) {
        bf16x8 w0;
#pragma unroll
        for (int e = 0; e < 4; ++e) {
          w0[e]     = (short)f2bf(av[s][0][e]);
          w0[4 + e] = (short)f2bf(av[s][1][e]);
        }
        *(bf16x8*)&As[s][aoff + asw] = w0;
      }
    }
    // stage B (L2-resident)
#pragma unroll
    for (int s = 0; s < 4; ++s) {
      if (s < nsub) {
#pragma unroll
        for (int j = 0; j < 4; ++j)
          gload_lds16(b_src[j] + kbase + s * 64, b_dst[j] + (size_t)s * (128 * 64));
      }
    }
    __syncthreads();                  // drain: B gloads + A ds_writes
    if (c + 1 < NCH) LOADA_CHUNK(kbase + 256);   // next A flies under compute
    const int nks = (c < 5) ? 8 : 6;
#pragma unroll
    for (int kk = 0; kk < 8; ++kk) {
      if (kk < nks) {
        const int sub = kk >> 1;
        const int sbase = (kk & 1) * 4 + (lane >> 4);  // logical 16B slot 0..7
        bf16x8 a, b[4];
        {
          int r = wr * 16 + (lane & 15);
          int s2 = sbase ^ (r & 7);
          a = *(const bf16x8*)&As[sub][r * 64 + s2 * 8];
        }
#pragma unroll
        for (int n = 0; n < 4; ++n) {
          int r = wc * 64 + n * 16 + (lane & 15);
          int s2 = sbase ^ (r & 7);
          b[n] = *(const bf16x8*)&Bs[sub][r * 64 + s2 * 8];
        }
#pragma unroll
        for (int n = 0; n < 4; ++n)
          acc[n] = __builtin_amdgcn_mfma_f32_16x16x32_bf16(a, b[n], acc[n], 0, 0, 0);
      }
    }
    __syncthreads();                  // all LDS reads done; next A-loads drained here (hidden)
  }
#undef LOADA_CHUNK

  // epilogue: D frag n: row = (lane>>4)*4 + reg, col = lane&15
  {
    int rbase = row0 + wr * 16 + (lane >> 4) * 4;
#pragma unroll
    for (int n = 0; n < 4; ++n) {
      int col = wc * 64 + n * 16 + (lane & 15);
#pragma unroll
      for (int r = 0; r < 4; ++r) {
        int grow = rbase + r;
        if (grow < N_NODES) h1pre[(size_t)grow * 128 + col] = acc[n][r];
      }
    }
  }
}

// ---------------- CSR build ----------------
__global__ void k_hist(const int* __restrict__ ei, int* __restrict__ deg) {
  int e = blockIdx.x * blockDim.x + threadIdx.x;
  if (e < N_EDGES) atomicAdd(&deg[ei[N_EDGES + e]], 1);
}

__global__ __launch_bounds__(256) void k_scan_a(const int* __restrict__ deg,
                                                int* __restrict__ off,
                                                int* __restrict__ blksum) {
  __shared__ int sd[256];
  const int t = threadIdx.x;
  const int base = blockIdx.x * 2048 + t * 8;
  int v[8];
  int s = 0;
#pragma unroll
  for (int j = 0; j < 8; ++j) {
    int i = base + j;
    v[j] = (i < N_NODES) ? deg[i] : 0;
    s += v[j];
  }
  sd[t] = s;
  __syncthreads();
  for (int o = 1; o < 256; o <<= 1) {
    int u = (t >= o) ? sd[t - o] : 0;
    __syncthreads();
    sd[t] += u;
    __syncthreads();
  }
  int excl = sd[t] - s;
#pragma unroll
  for (int j = 0; j < 8; ++j) {
    int i = base + j;
    if (i < N_NODES) off[i] = excl;
    excl += v[j];
  }
  if (t == 255) blksum[blockIdx.x] = sd[255];
}

// scan_c with fused chunk-offset computation: each 256-thread block lies in one
// 2048-chunk; wave 0 reduces blksum[0..c-1] via shfl.
__global__ __launch_bounds__(256) void k_scan_c(int* __restrict__ off, int* __restrict__ cur,
                                                const int* __restrict__ blksum) {
  __shared__ int boffs;
  const int c = blockIdx.x >> 3;            // 2048/256
  if (threadIdx.x < 64) {
    int v = ((int)threadIdx.x < c) ? blksum[threadIdx.x] : 0;
#pragma unroll
    for (int o = 32; o > 0; o >>= 1) v += __shfl_xor(v, o);
    if (threadIdx.x == 0) boffs = v;
  }
  __syncthreads();
  int i = blockIdx.x * 256 + threadIdx.x;
  if (i < N_NODES) {
    int v = off[i] + boffs;
    off[i] = v;
    cur[i] = v;
  }
}

__global__ void k_fill(const int* __restrict__ ei, int* __restrict__ cur,
                       int* __restrict__ esrc) {
  int e = blockIdx.x * blockDim.x + threadIdx.x;
  if (e < N_EDGES) {
    int s = ei[e];
    int d = ei[N_EDGES + e];
    int slot = atomicAdd(&cur[d], 1);
    esrc[slot] = s;
  }
}

// ---------------- aggregate layer 1: one wave per dst, 8-way unrolled gather ----------------
__global__ __launch_bounds__(256) void k_agg1(const float* __restrict__ h1pre,
                                              const int* __restrict__ off,
                                              const int* __restrict__ deg,
                                              const int* __restrict__ esrc,
                                              const float* __restrict__ b1,
                                              float* __restrict__ h1) {
  const int lane = threadIdx.x & 63;
  const int d = blockIdx.x * 4 + (threadIdx.x >> 6);
  if (d >= N_NODES) return;
  const int dg = deg[d];
  const int base = off[d];
  float a0 = 0.f, a1 = 0.f, a2 = 0.f, a3 = 0.f;
  float a4 = 0.f, a5 = 0.f, a6 = 0.f, a7 = 0.f;
  int j = 0;
  for (; j + 8 <= dg; j += 8) {
    int s0 = esrc[base + j],     s1 = esrc[base + j + 1];
    int s2 = esrc[base + j + 2], s3 = esrc[base + j + 3];
    int s4 = esrc[base + j + 4], s5 = esrc[base + j + 5];
    int s6 = esrc[base + j + 6], s7 = esrc[base + j + 7];
    a0 += h1pre[(size_t)s0 * 128 + lane];
    a1 += h1pre[(size_t)s1 * 128 + lane];
    a2 += h1pre[(size_t)s2 * 128 + lane];
    a3 += h1pre[(size_t)s3 * 128 + lane];
    a4 += h1pre[(size_t)s4 * 128 + lane];
    a5 += h1pre[(size_t)s5 * 128 + lane];
    a6 += h1pre[(size_t)s6 * 128 + lane];
    a7 += h1pre[(size_t)s7 * 128 + lane];
  }
  for (; j + 4 <= dg; j += 4) {
    int s0 = esrc[base + j],     s1 = esrc[base + j + 1];
    int s2 = esrc[base + j + 2], s3 = esrc[base + j + 3];
    a0 += h1pre[(size_t)s0 * 128 + lane];
    a1 += h1pre[(size_t)s1 * 128 + lane];
    a2 += h1pre[(size_t)s2 * 128 + lane];
    a3 += h1pre[(size_t)s3 * 128 + lane];
  }
  for (; j < dg; ++j) a0 += h1pre[(size_t)esrc[base + j] * 128 + lane];
  float acc = ((a0 + a1) + (a2 + a3)) + ((a4 + a5) + (a6 + a7));
  const float inv = (dg > 0) ? 1.f / (float)dg : 0.f;
  h1[(size_t)d * 64 + lane] = acc * inv + b1[lane] + h1pre[(size_t)d * 128 + 64 + lane];
}

// ---------------- GEMM2: h1[50000,64] @ [W2_l|W2_r][64,64] -> m2[50000,64] ----------------
__global__ __launch_bounds__(256) void k_gemm2(const float* __restrict__ h1,
                                               const float* __restrict__ W2l,
                                               const float* __restrict__ W2r,
                                               float* __restrict__ m2) {
  __shared__ __align__(16) float Ws[64][68];
  __shared__ __align__(16) float Hs[32][68];
  const int t = threadIdx.x;
#pragma unroll
  for (int i = 0; i < 16; ++i) {
    int idx = t + 256 * i;
    int k = idx >> 6, c = idx & 63;
    Ws[k][c] = (c < 32) ? W2l[k * 32 + c] : W2r[k * 32 + (c - 32)];
  }
  const int r0 = blockIdx.x * 32;
#pragma unroll
  for (int i = 0; i < 8; ++i) {
    int idx = t + 256 * i;
    int r = idx >> 6, c = idx & 63;
    int gr = r0 + r;
    Hs[r][c] = (gr < N_NODES) ? h1[(size_t)gr * 64 + c] : 0.f;
  }
  __syncthreads();
  const int rl = t >> 3;
  const int c0 = (t & 7) * 8;
  float acc[8] = {};
#pragma unroll 8
  for (int k = 0; k < 64; ++k) {
    float hv = Hs[rl][k];
#pragma unroll
    for (int j = 0; j < 8; ++j) acc[j] = fmaf(hv, Ws[k][c0 + j], acc[j]);
  }
  const int gr = r0 + rl;
  if (gr < N_NODES) {
    *(float4*)(&m2[(size_t)gr * 64 + c0])     = make_float4(acc[0], acc[1], acc[2], acc[3]);
    *(float4*)(&m2[(size_t)gr * 64 + c0 + 4]) = make_float4(acc[4], acc[5], acc[6], acc[7]);
  }
}

// ---------------- aggregate layer 2 + relu + log_softmax, 8-way unrolled ----------------
__global__ __launch_bounds__(256) void k_agg2(const float* __restrict__ m2,
                                              const int* __restrict__ off,
                                              const int* __restrict__ deg,
                                              const int* __restrict__ esrc,
                                              const float* __restrict__ b2,
                                              float* __restrict__ out) {
  const int lane = threadIdx.x & 63;
  const int half = lane >> 5;
  const int f = lane & 31;
  const int d = blockIdx.x * 8 + ((threadIdx.x >> 6) << 1) + half;  // 50000 % 8 == 0
  const int dg = deg[d];
  const int base = off[d];
  float a0 = 0.f, a1 = 0.f, a2 = 0.f, a3 = 0.f;
  float a4 = 0.f, a5 = 0.f, a6 = 0.f, a7 = 0.f;
  int j = 0;
  for (; j + 8 <= dg; j += 8) {
    int s0 = esrc[base + j],     s1 = esrc[base + j + 1];
    int s2 = esrc[base + j + 2], s3 = esrc[base + j + 3];
    int s4 = esrc[base + j + 4], s5 = esrc[base + j + 5];
    int s6 = esrc[base + j + 6], s7 = esrc[base + j + 7];
    a0 += m2[(size_t)s0 * 64 + f];
    a1 += m2[(size_t)s1 * 64 + f];
    a2 += m2[(size_t)s2 * 64 + f];
    a3 += m2[(size_t)s3 * 64 + f];
    a4 += m2[(size_t)s4 * 64 + f];
    a5 += m2[(size_t)s5 * 64 + f];
    a6 += m2[(size_t)s6 * 64 + f];
    a7 += m2[(size_t)s7 * 64 + f];
  }
  for (; j + 4 <= dg; j += 4) {
    int s0 = esrc[base + j],     s1 = esrc[base + j + 1];
    int s2 = esrc[base + j + 2], s3 = esrc[base + j + 3];
    a0 += m2[(size_t)s0 * 64 + f];
    a1 += m2[(size_t)s1 * 64 + f];
    a2 += m2[(size_t)s2 * 64 + f];
    a3 += m2[(size_t)s3 * 64 + f];
  }
  for (; j < dg; ++j) a0 += m2[(size_t)esrc[base + j] * 64 + f];
  float acc = ((a0 + a1) + (a2 + a3)) + ((a4 + a5) + (a6 + a7));
  const float inv = (dg > 0) ? 1.f / (float)dg : 0.f;
  float v = acc * inv + b2[f] + m2[(size_t)d * 64 + 32 + f];
  v = fmaxf(v, 0.f);
  float m = v;
#pragma unroll
  for (int o = 16; o > 0; o >>= 1) m = fmaxf(m, __shfl_xor(m, o, 32));
  float e = expf(v - m);
  float sum = e;
#pragma unroll
  for (int o = 16; o > 0; o >>= 1) sum += __shfl_xor(sum, o, 32);
  out[(size_t)d * 32 + f] = v - m - logf(sum);
}

extern "C" void kernel_launch(void* const* d_in, const int* in_sizes, int n_in,
                              void* d_out, int out_size, void* d_ws, size_t ws_size,
                              hipStream_t stream) {
  const float* x   = (const float*)d_in[0];
  const int*   ei  = (const int*)d_in[1];
  const float* W1l = (const float*)d_in[2];
  const float* b1  = (const float*)d_in[3];
  const float* W1r = (const float*)d_in[4];
  const float* W2l = (const float*)d_in[5];
  const float* b2  = (const float*)d_in[6];
  const float* W2r = (const float*)d_in[7];
  float* out = (float*)d_out;

  char* ws = (char*)d_ws;
  float*  h1pre = (float*)(ws + OFF_H1PRE);
  float*  h1    = (float*)(ws + OFF_H1);
  float*  m2    = (float*)(ws + OFF_M2);
  int*    deg   = (int*)(ws + OFF_DEG);
  int*    off   = (int*)(ws + OFF_OFFS);
  int*    cur   = (int*)(ws + OFF_CUR);
  int*    esrc  = (int*)(ws + OFF_ESRC);
  int*    bsum  = (int*)(ws + OFF_BSUM);
  ushort* Wt    = (ushort*)(ws + OFF_WT);

  k_zero_deg<<<(N_NODES + 255) / 256, 256, 0, stream>>>(deg);

  {
    dim3 g(128, (KP + 255) / 256);
    k_prep_w<<<g, 256, 0, stream>>>(W1l, W1r, Wt);
  }
  k_gemm1c<<<(N_NODES + 31) / 32, 256, 0, stream>>>(x, Wt, h1pre);

  k_hist<<<(N_EDGES + 255) / 256, 256, 0, stream>>>(ei, deg);
  k_scan_a<<<25, 256, 0, stream>>>(deg, off, bsum);
  k_scan_c<<<(N_NODES + 255) / 256, 256, 0, stream>>>(off, cur, bsum);
  k_fill<<<(N_EDGES + 255) / 256, 256, 0, stream>>>(ei, cur, esrc);

  k_agg1<<<N_NODES / 4, 256, 0, stream>>>(h1pre, off, deg, esrc, b1, h1);
  k_gemm2<<<(N_NODES + 31) / 32, 256, 0, stream>>>(h1, W2l, W2r, m2);
  k_agg2<<<N_NODES / 8, 256, 0, stream>>>(m2, off, deg, esrc, b2, out);
}